// Round 2
// baseline (19158.176 us; speedup 1.0000x reference)
//
#include <hip/hip_runtime.h>

#define S_  1024
#define B_  64
#define P_  32

typedef _Float16 f16;
typedef unsigned int u32;
typedef _Float16 half2_t __attribute__((ext_vector_type(2)));
typedef _Float16 half8_t __attribute__((ext_vector_type(8)));

__device__ __forceinline__ float dot8(half8_t w, half8_t h, float acc) {
#if __has_builtin(__builtin_amdgcn_fdot2)
    acc = __builtin_amdgcn_fdot2((half2_t){w[0], w[1]}, (half2_t){h[0], h[1]}, acc, false);
    acc = __builtin_amdgcn_fdot2((half2_t){w[2], w[3]}, (half2_t){h[2], h[3]}, acc, false);
    acc = __builtin_amdgcn_fdot2((half2_t){w[4], w[5]}, (half2_t){h[4], h[5]}, acc, false);
    acc = __builtin_amdgcn_fdot2((half2_t){w[6], w[7]}, (half2_t){h[6], h[7]}, acc, false);
#else
    #pragma unroll
    for (int j = 0; j < 8; ++j) acc += (float)w[j] * (float)h[j];
#endif
    return acc;
}

__device__ __forceinline__ float sigf(float x) { return 1.f / (1.f + expf(-x)); }

// ---- prep: fused weight rows Wcomb[dir][row][0:128)=Wih, [128:384)=Whh (f16); bias2 = bih+bhh ----
__global__ void k_prep_w(const float* __restrict__ wih_f, const float* __restrict__ whh_f,
                         const float* __restrict__ bih_f, const float* __restrict__ bhh_f,
                         const float* __restrict__ wih_b, const float* __restrict__ whh_b,
                         const float* __restrict__ bih_b, const float* __restrict__ bhh_b,
                         f16* __restrict__ Wcomb, float* __restrict__ bias2) {
    int rowg = blockIdx.x;          // 0..2047
    int dir = rowg >> 10;
    int r = rowg & 1023;
    int tid = threadIdx.x;          // 384 threads
    const float* wih = dir ? wih_b : wih_f;
    const float* whh = dir ? whh_b : whh_f;
    float v;
    if (tid < 128) v = wih[r * 128 + tid];
    else           v = whh[r * 256 + (tid - 128)];
    Wcomb[(size_t)rowg * 384 + tid] = (f16)v;
    if (tid == 0) {
        const float* bi = dir ? bih_b : bih_f;
        const float* bh = dir ? bhh_b : bhh_f;
        bias2[rowg] = bi[r] + bh[r];
    }
}

// ---- embedding gather -> f16 X[b][t][128] ----
__global__ void k_gather(const int* __restrict__ ids, const float* __restrict__ emb,
                         f16* __restrict__ X) {
    int m = blockIdx.x * 2 + (threadIdx.x >> 7);
    int k = threadIdx.x & 127;
    int id = ids[m];
    X[(size_t)m * 128 + k] = (f16)emb[(size_t)id * 128 + k];
}

// ---- zero the sync flags (ws is poisoned 0xAA before every launch) ----
__global__ void k_zero(u32* __restrict__ flags) {
    flags[threadIdx.x] = 0u;
}

// ---- recurrence: 256 blocks = 2 dir x 64 batch x 2 gate-halves; weights register-resident ----
__global__ __launch_bounds__(512, 2) void k_lstm(
        const f16* __restrict__ Wcomb,   // [2][1024][384]
        const float* __restrict__ bias2, // [2][1024]
        const f16* __restrict__ X,       // [64][1024][128]
        const float* __restrict__ fcw,   // [512]
        f16* __restrict__ Hx,            // [2][64][2][2][128]  (dir,b,half,parity,u)
        u32* __restrict__ flags,         // [2][64][2]
        float* __restrict__ Svp) {       // [2half][2dir][64][1024]
    __shared__ __align__(16) f16 sh_x[2][128];
    __shared__ __align__(16) f16 sh_h[256];
    __shared__ float zbuf[4][128];

    const int blk  = blockIdx.x;
    const int dir  = blk >> 7;
    const int half = (blk >> 6) & 1;
    const int b    = blk & 63;
    const int tid  = threadIdx.x;
    const int g    = tid >> 7;      // gate 0..3 (i,f,g,o) — wave-uniform
    const int up   = tid & 127;     // u' within the half
    const int row  = g * 256 + half * 128 + up;   // gate row in [0,1024)

    // weights: 48 chunks of 8 f16 = 192 VGPRs, loaded once (L2-broadcast, one-time)
    const half8_t* wrow = (const half8_t*)(Wcomb + ((size_t)(dir * 1024 + row)) * 384);
    half8_t w[48];
    #pragma unroll
    for (int c = 0; c < 48; ++c) w[c] = wrow[c];

    const float bias = bias2[dir * 1024 + row];

    const f16* Xb = X + (size_t)b * S_ * 128;
    const int fidx_own = (dir * 64 + b) * 2 + half;
    const int fidx_par = fidx_own ^ 1;
    f16*       hx_own = Hx + (size_t)fidx_own * 2 * 128;
    const f16* hx_par = Hx + (size_t)fidx_par * 2 * 128;

    // wave-0 combine state (2 u's per lane)
    float c0 = 0.f, c1 = 0.f, fc0 = 0.f, fc1 = 0.f;
    if (tid < 64) {
        fc0 = fcw[dir * 256 + half * 128 + 2 * tid];
        fc1 = fcw[dir * 256 + half * 128 + 2 * tid + 1];
    }

    // init LDS: h_0 = 0 everywhere; stage x at t0
    if (tid < 128) ((u32*)sh_h)[tid] = 0u;
    const int t0 = dir ? (S_ - 1) : 0;
    if (tid < 16)
        *(half8_t*)&sh_x[0][tid * 8] = *(const half8_t*)&Xb[(size_t)t0 * 128 + tid * 8];
    __syncthreads();

    for (int s = 0; s < S_; ++s) {
        const int t = dir ? (S_ - 1 - s) : s;
        const int par = s & 1;

        // prefetch x_{t_next} into regs (lanes 64..79); written to LDS after barrier-2
        half8_t xpre = {};
        if (s + 1 < S_ && tid >= 64 && tid < 80) {
            int tn = dir ? (t - 1) : (t + 1);
            xpre = *(const half8_t*)&Xb[(size_t)tn * 128 + (tid - 64) * 8];
        }

        // ---- phase 1: x chunks + own-half h chunks (partner h still in flight) ----
        float a0 = 0.f, a1 = 0.f, a2 = 0.f, a3 = 0.f;
        #pragma unroll
        for (int j = 0; j < 16; j += 4) {
            a0 = dot8(w[j + 0], *(const half8_t*)&sh_x[par][(j + 0) * 8], a0);
            a1 = dot8(w[j + 1], *(const half8_t*)&sh_x[par][(j + 1) * 8], a1);
            a2 = dot8(w[j + 2], *(const half8_t*)&sh_x[par][(j + 2) * 8], a2);
            a3 = dot8(w[j + 3], *(const half8_t*)&sh_x[par][(j + 3) * 8], a3);
        }
        {
            const int wb = 16 + half * 16;
            const int hb = half * 128;
            #pragma unroll
            for (int j = 0; j < 16; j += 4) {
                a0 = dot8(w[wb + j + 0], *(const half8_t*)&sh_h[hb + (j + 0) * 8], a0);
                a1 = dot8(w[wb + j + 1], *(const half8_t*)&sh_h[hb + (j + 1) * 8], a1);
                a2 = dot8(w[wb + j + 2], *(const half8_t*)&sh_h[hb + (j + 2) * 8], a2);
                a3 = dot8(w[wb + j + 3], *(const half8_t*)&sh_h[hb + (j + 3) * 8], a3);
            }
        }

        // ---- wave 0: wait for partner h_s, stage it into LDS ----
        if (s > 0 && tid < 64) {
            if (tid == 0) {
                while (__hip_atomic_load(&flags[fidx_par], __ATOMIC_ACQUIRE,
                                         __HIP_MEMORY_SCOPE_AGENT) < (u32)s)
                    __builtin_amdgcn_s_sleep(1);
            }
            if (tid < 16)
                *(half8_t*)&sh_h[(1 - half) * 128 + tid * 8] =
                    *(const half8_t*)&hx_par[(size_t)(s & 1) * 128 + tid * 8];
        }
        __syncthreads();   // barrier 1: partner h staged

        // ---- phase 3: partner-half h chunks ----
        {
            const int wb = 16 + (1 - half) * 16;
            const int hb = (1 - half) * 128;
            #pragma unroll
            for (int j = 0; j < 16; j += 4) {
                a0 = dot8(w[wb + j + 0], *(const half8_t*)&sh_h[hb + (j + 0) * 8], a0);
                a1 = dot8(w[wb + j + 1], *(const half8_t*)&sh_h[hb + (j + 1) * 8], a1);
                a2 = dot8(w[wb + j + 2], *(const half8_t*)&sh_h[hb + (j + 2) * 8], a2);
                a3 = dot8(w[wb + j + 3], *(const half8_t*)&sh_h[hb + (j + 3) * 8], a3);
            }
        }
        float z = a0 + a1 + a2 + a3 + bias;
        float act = (g == 2) ? tanhf(z) : sigf(z);
        zbuf[g][up] = act;
        __syncthreads();   // barrier 2: all gate activations ready

        // ---- wave 0: combine (2 u's/lane), publish h, partial s_t ----
        if (tid < 64) {
            const int u0 = 2 * tid, u1 = u0 + 1;
            float i0 = zbuf[0][u0], f0 = zbuf[1][u0], g0 = zbuf[2][u0], o0 = zbuf[3][u0];
            float i1 = zbuf[0][u1], f1 = zbuf[1][u1], g1 = zbuf[2][u1], o1 = zbuf[3][u1];
            c0 = f0 * c0 + i0 * g0;
            c1 = f1 * c1 + i1 * g1;
            float h0 = o0 * tanhf(c0);
            float h1 = o1 * tanhf(c1);
            f16 h0h = (f16)h0, h1h = (f16)h1;
            u32 packed = (u32)__builtin_bit_cast(unsigned short, h0h)
                       | ((u32)__builtin_bit_cast(unsigned short, h1h) << 16);
            ((u32*)&sh_h[half * 128])[tid] = packed;                    // own half for next step
            ((u32*)&hx_own[(size_t)((s + 1) & 1) * 128])[tid] = packed; // publish to partner
            float ps = h0 * fc0 + h1 * fc1;
            #pragma unroll
            for (int off = 32; off > 0; off >>= 1) ps += __shfl_down(ps, off);
            if (tid == 0) {
                __hip_atomic_store(&flags[fidx_own], (u32)(s + 1), __ATOMIC_RELEASE,
                                   __HIP_MEMORY_SCOPE_AGENT);
                Svp[(((size_t)half * 2 + dir) * 64 + b) * S_ + t] = ps;
            }
        }
        // x prefetch -> LDS (other parity buffer)
        if (s + 1 < S_ && tid >= 64 && tid < 80)
            *(half8_t*)&sh_x[par ^ 1][(tid - 64) * 8] = xpre;
        __syncthreads();   // barrier 3: h_{s+1} own half + next x staged
    }
}

// ---- span pooling + FC ----
__global__ __launch_bounds__(256) void k_pool(const float* __restrict__ Svp, // [2][2][64][1024]
                                              const int* __restrict__ om,    // [64][1024][2]
                                              const int* __restrict__ pos,   // [64][32][2]
                                              const float* __restrict__ fcb,
                                              float* __restrict__ out) {     // [64][32]
    __shared__ float red[4][2];
    int bp = blockIdx.x;
    int b = bp >> 5, p = bp & 31;
    int ps = pos[(b * P_ + p) * 2];
    int pe = pos[(b * P_ + p) * 2 + 1];
    int tid = threadIdx.x;
    float sum = 0.f, cnt = 0.f;
    for (int j = tid; j < S_; j += 256) {
        int os = om[((size_t)b * S_ + j) * 2];
        int oe = om[((size_t)b * S_ + j) * 2 + 1];
        if (os >= ps && oe <= pe) {
            size_t base = (size_t)b * S_ + j;
            sum += Svp[0 * 65536 + base] + Svp[1 * 65536 + base]
                 + Svp[2 * 65536 + base] + Svp[3 * 65536 + base];
            cnt += 1.f;
        }
    }
    #pragma unroll
    for (int off = 32; off > 0; off >>= 1) {
        sum += __shfl_down(sum, off);
        cnt += __shfl_down(cnt, off);
    }
    if ((tid & 63) == 0) { red[tid >> 6][0] = sum; red[tid >> 6][1] = cnt; }
    __syncthreads();
    if (tid == 0) {
        sum = red[0][0] + red[1][0] + red[2][0] + red[3][0];
        cnt = red[0][1] + red[1][1] + red[2][1] + red[3][1];
        bool valid = (cnt > 0.f) && !(ps == 0 && pe == 0);
        float v = valid ? (sum / fmaxf(cnt, 1.f)) : 0.f;
        out[b * P_ + p] = v + fcb[0];
    }
}

extern "C" void kernel_launch(void* const* d_in, const int* in_sizes, int n_in,
                              void* d_out, int out_size, void* d_ws, size_t ws_size,
                              hipStream_t stream) {
    const float* emb   = (const float*)d_in[0];
    const float* wih_f = (const float*)d_in[1];
    const float* whh_f = (const float*)d_in[2];
    const float* bih_f = (const float*)d_in[3];
    const float* bhh_f = (const float*)d_in[4];
    const float* wih_b = (const float*)d_in[5];
    const float* whh_b = (const float*)d_in[6];
    const float* bih_b = (const float*)d_in[7];
    const float* bhh_b = (const float*)d_in[8];
    const float* fc_w  = (const float*)d_in[9];
    const float* fc_b  = (const float*)d_in[10];
    const int* ids     = (const int*)d_in[11];
    const int* om      = (const int*)d_in[13];
    const int* pos     = (const int*)d_in[14];

    char* ws = (char*)d_ws;
    f16*   X     = (f16*)(ws + 0);            // 64*1024*128*2   = 16,777,216
    f16*   Wcomb = (f16*)(ws + 16777216);     // 2*1024*384*2    =  1,572,864
    float* bias2 = (float*)(ws + 18350080);   // 2048*4          =      8,192
    f16*   Hx    = (f16*)(ws + 18358272);     // 2*64*2*2*128*2  =    131,072
    u32*   flags = (u32*)(ws + 18489344);     // 256*4           =      1,024
    float* Svp   = (float*)(ws + 18490368);   // 4*64*1024*4     =  1,048,576
    float* out   = (float*)d_out;             // total ws use ≈ 19.5 MB

    k_prep_w<<<2048, 384, 0, stream>>>(wih_f, whh_f, bih_f, bhh_f,
                                       wih_b, whh_b, bih_b, bhh_b, Wcomb, bias2);
    k_gather<<<32768, 256, 0, stream>>>(ids, emb, X);
    k_zero<<<1, 256, 0, stream>>>(flags);
    k_lstm<<<256, 512, 0, stream>>>(Wcomb, bias2, X, fc_w, Hx, flags, Svp);
    k_pool<<<2048, 256, 0, stream>>>(Svp, om, pos, fc_b, out);
}

// Round 3
// 17492.889 us; speedup vs baseline: 1.0952x; 1.0952x over previous
//
#include <hip/hip_runtime.h>

#define S_  1024
#define B_  64
#define P_  32

typedef _Float16 f16;
typedef unsigned int u32;
typedef _Float16 half2_t __attribute__((ext_vector_type(2)));
typedef _Float16 half8_t __attribute__((ext_vector_type(8)));

__device__ __forceinline__ float dot8(half8_t w, half8_t h, float acc) {
#if __has_builtin(__builtin_amdgcn_fdot2)
    acc = __builtin_amdgcn_fdot2((half2_t){w[0], w[1]}, (half2_t){h[0], h[1]}, acc, false);
    acc = __builtin_amdgcn_fdot2((half2_t){w[2], w[3]}, (half2_t){h[2], h[3]}, acc, false);
    acc = __builtin_amdgcn_fdot2((half2_t){w[4], w[5]}, (half2_t){h[4], h[5]}, acc, false);
    acc = __builtin_amdgcn_fdot2((half2_t){w[6], w[7]}, (half2_t){h[6], h[7]}, acc, false);
#else
    #pragma unroll
    for (int j = 0; j < 8; ++j) acc += (float)w[j] * (float)h[j];
#endif
    return acc;
}

__device__ __forceinline__ float fast_sig(float x)  { return 1.f / (1.f + __expf(-x)); }
__device__ __forceinline__ float fast_tanh(float x) { return 1.f - 2.f / (1.f + __expf(2.f * x)); }

// ---- prep: swizzled fused rows  Wsw[dir][half][ga][ab][c(48)][up(128)][8] (f16) ----
__global__ void k_prep_w(const float* __restrict__ wih_f, const float* __restrict__ whh_f,
                         const float* __restrict__ bih_f, const float* __restrict__ bhh_f,
                         const float* __restrict__ wih_b, const float* __restrict__ whh_b,
                         const float* __restrict__ bih_b, const float* __restrict__ bhh_b,
                         f16* __restrict__ Wsw, float* __restrict__ bias2) {
    int rowg = blockIdx.x;          // 0..2047
    int dir = rowg >> 10;
    int r = rowg & 1023;
    int col = threadIdx.x;          // 0..383
    const float* wih = dir ? wih_b : wih_f;
    const float* whh = dir ? whh_b : whh_f;
    float v = (col < 128) ? wih[r * 128 + col] : whh[r * 256 + (col - 128)];
    int g = r >> 8, halfb = (r >> 7) & 1, up = r & 127;
    int ga = g & 1, ab = g >> 1;
    int c = col >> 3, j = col & 7;
    Wsw[((((((size_t)dir * 2 + halfb) * 2 + ga) * 2 + ab) * 48 + c) * 128 + up) * 8 + j] = (f16)v;
    if (col == 0) {
        const float* bi = dir ? bih_b : bih_f;
        const float* bh = dir ? bhh_b : bhh_f;
        bias2[rowg] = bi[r] + bh[r];
    }
}

// ---- embedding gather -> f16 X[b][t][128] ----
__global__ void k_gather(const int* __restrict__ ids, const float* __restrict__ emb,
                         f16* __restrict__ X) {
    int m = blockIdx.x * 2 + (threadIdx.x >> 7);
    int k = threadIdx.x & 127;
    int id = ids[m];
    X[(size_t)m * 128 + k] = (f16)emb[(size_t)id * 128 + k];
}

// ---- zero the sync flags (ws is poisoned 0xAA before every launch) ----
__global__ void k_zero(u32* __restrict__ flags) {
    flags[threadIdx.x] = 0u;
}

// ---- recurrence: 256 blocks = 2 dir x 2 half x 64 batch; 256 thr; 2 rows/thread in regs ----
__global__ __launch_bounds__(256, 1) void k_lstm(
        const f16* __restrict__ Wsw,     // swizzled weights
        const float* __restrict__ bias2, // [2][1024]
        const f16* __restrict__ X,       // [64][1024][128]
        const float* __restrict__ fcw,   // [512]
        f16* __restrict__ Hx,            // [256 slots][2 parity][128]
        u32* __restrict__ flags,         // [256]
        float* __restrict__ Svp) {       // [4][64][1024]
    __shared__ __align__(16) f16 sh_h[256];     // [half0 u128 | half1 u128]
    __shared__ float zbuf[4][128];              // gate activations for own half

    const int blk  = blockIdx.x;
    const int dir  = blk >> 7;
    const int half = (blk >> 6) & 1;
    const int b    = blk & 63;
    const int tid  = threadIdx.x;
    const int ga   = tid >> 7;      // 0: rows {i,g}, 1: rows {f,o}
    const int up   = tid & 127;

    // ---- weights: 2 rows x 48 chunks of 8 f16 = 384 VGPRs, loaded once (coalesced) ----
    const half8_t* wp = (const half8_t*)Wsw;
    const size_t baseA = ((((size_t)dir * 2 + half) * 2 + ga) * 2 + 0) * 48 * 128 + up;
    const size_t baseB = ((((size_t)dir * 2 + half) * 2 + ga) * 2 + 1) * 48 * 128 + up;
    half8_t wA[48], wB[48];
    #pragma unroll
    for (int c = 0; c < 48; ++c) wA[c] = wp[baseA + (size_t)c * 128];
    #pragma unroll
    for (int c = 0; c < 48; ++c) wB[c] = wp[baseB + (size_t)c * 128];

    const int rowA = ga * 256 + half * 128 + up;        // gate ga   (i or f)
    const int rowB = (ga + 2) * 256 + half * 128 + up;  // gate ga+2 (g or o)
    const float biasA = bias2[dir * 1024 + rowA];
    const float biasB = bias2[dir * 1024 + rowB];

    const f16* Xb = X + (size_t)b * S_ * 128;
    const int fidx_own = (dir * 64 + b) * 2 + half;
    const int fidx_par = fidx_own ^ 1;
    f16*       hx_own = Hx + (size_t)fidx_own * 2 * 128;
    const f16* hx_par = Hx + (size_t)fidx_par * 2 * 128;

    // combine-wave state (wave 0, 2 u's per lane)
    float c0 = 0.f, c1 = 0.f, fc0 = 0.f, fc1 = 0.f;
    if (tid < 64) {
        fc0 = fcw[dir * 256 + half * 128 + 2 * tid];
        fc1 = fcw[dir * 256 + half * 128 + 2 * tid + 1];
    }

    // init LDS h = 0 (both halves)
    if (tid < 128) ((u32*)sh_h)[tid] = 0u;
    __syncthreads();

    const half8_t* shh = (const half8_t*)sh_h;    // 32 chunks of 8 f16
    const int ownc = half * 16;
    const int parc = (1 - half) * 16;

    for (int s = 0; s < S_; ++s) {
        const int t = dir ? (S_ - 1 - s) : s;

        float aA0 = 0.f, aA1 = 0.f, aB0 = 0.f, aB1 = 0.f;

        // ---- x chunks: wave-uniform global loads (off the LDS pipe) ----
        const half8_t* xrow = (const half8_t*)&Xb[(size_t)t * 128];
        half8_t xc[16];
        #pragma unroll
        for (int c = 0; c < 16; ++c) xc[c] = xrow[c];

        // ---- own-half h dots (LDS ready from prev step) ----
        #pragma unroll
        for (int c = 0; c < 16; c += 2) {
            half8_t h0 = shh[ownc + c];
            half8_t h1 = shh[ownc + c + 1];
            aA0 = dot8(wA[16 + half * 16 + c],     h0, aA0);
            aB0 = dot8(wB[16 + half * 16 + c],     h0, aB0);
            aA1 = dot8(wA[16 + half * 16 + c + 1], h1, aA1);
            aB1 = dot8(wB[16 + half * 16 + c + 1], h1, aB1);
        }
        // ---- x dots ----
        #pragma unroll
        for (int c = 0; c < 16; c += 2) {
            aA0 = dot8(wA[c],     xc[c],     aA0);
            aB0 = dot8(wB[c],     xc[c],     aB0);
            aA1 = dot8(wA[c + 1], xc[c + 1], aA1);
            aB1 = dot8(wB[c + 1], xc[c + 1], aB1);
        }

        // ---- wave 0: wait for partner h_s, stage into LDS ----
        if (s > 0 && tid < 64) {
            if (tid == 0) {
                while (__hip_atomic_load(&flags[fidx_par], __ATOMIC_ACQUIRE,
                                         __HIP_MEMORY_SCOPE_AGENT) < (u32)s)
                    __builtin_amdgcn_s_sleep(1);
            }
            if (tid < 16)
                *(half8_t*)&sh_h[(1 - half) * 128 + tid * 8] =
                    *(const half8_t*)&hx_par[(size_t)(s & 1) * 128 + tid * 8];
        }
        __syncthreads();   // B1: partner h staged

        // ---- partner-half h dots ----
        #pragma unroll
        for (int c = 0; c < 16; c += 2) {
            half8_t h0 = shh[parc + c];
            half8_t h1 = shh[parc + c + 1];
            aA0 = dot8(wA[16 + (1 - half) * 16 + c],     h0, aA0);
            aB0 = dot8(wB[16 + (1 - half) * 16 + c],     h0, aB0);
            aA1 = dot8(wA[16 + (1 - half) * 16 + c + 1], h1, aA1);
            aB1 = dot8(wB[16 + (1 - half) * 16 + c + 1], h1, aB1);
        }

        float zA = aA0 + aA1 + biasA;                      // gate i (ga=0) or f (ga=1)
        float zB = aB0 + aB1 + biasB;                      // gate g (ga=0) or o (ga=1)
        zbuf[ga][up]     = fast_sig(zA);
        zbuf[ga + 2][up] = (ga == 0) ? fast_tanh(zB) : fast_sig(zB);
        __syncthreads();   // B2: all gate activations ready

        // ---- wave 0: combine (2 u's/lane), publish h, partial FC dot ----
        if (tid < 64) {
            const int u0 = 2 * tid, u1 = u0 + 1;
            float i0 = zbuf[0][u0], f0 = zbuf[1][u0], g0 = zbuf[2][u0], o0 = zbuf[3][u0];
            float i1 = zbuf[0][u1], f1 = zbuf[1][u1], g1 = zbuf[2][u1], o1 = zbuf[3][u1];
            c0 = f0 * c0 + i0 * g0;
            c1 = f1 * c1 + i1 * g1;
            float h0 = o0 * fast_tanh(c0);
            float h1 = o1 * fast_tanh(c1);
            f16 h0h = (f16)h0, h1h = (f16)h1;
            u32 packed = (u32)__builtin_bit_cast(unsigned short, h0h)
                       | ((u32)__builtin_bit_cast(unsigned short, h1h) << 16);
            ((u32*)&sh_h[half * 128])[tid] = packed;                    // own half for next step
            ((u32*)&hx_own[(size_t)((s + 1) & 1) * 128])[tid] = packed; // publish to partner
            float ps = h0 * fc0 + h1 * fc1;
            #pragma unroll
            for (int off = 32; off > 0; off >>= 1) ps += __shfl_down(ps, off);
            if (tid == 0) {
                __hip_atomic_store(&flags[fidx_own], (u32)(s + 1), __ATOMIC_RELEASE,
                                   __HIP_MEMORY_SCOPE_AGENT);
                Svp[(((size_t)half * 2 + dir) * 64 + b) * S_ + t] = ps;
            }
        }
        __syncthreads();   // B3: h_{s+1} own half staged; zbuf consumed
    }
}

// ---- span pooling + FC ----
__global__ __launch_bounds__(256) void k_pool(const float* __restrict__ Svp, // [4][64][1024]
                                              const int* __restrict__ om,    // [64][1024][2]
                                              const int* __restrict__ pos,   // [64][32][2]
                                              const float* __restrict__ fcb,
                                              float* __restrict__ out) {     // [64][32]
    __shared__ float red[4][2];
    int bp = blockIdx.x;
    int b = bp >> 5, p = bp & 31;
    int ps = pos[(b * P_ + p) * 2];
    int pe = pos[(b * P_ + p) * 2 + 1];
    int tid = threadIdx.x;
    float sum = 0.f, cnt = 0.f;
    for (int j = tid; j < S_; j += 256) {
        int os = om[((size_t)b * S_ + j) * 2];
        int oe = om[((size_t)b * S_ + j) * 2 + 1];
        if (os >= ps && oe <= pe) {
            size_t base = (size_t)b * S_ + j;
            sum += Svp[0 * 65536 + base] + Svp[1 * 65536 + base]
                 + Svp[2 * 65536 + base] + Svp[3 * 65536 + base];
            cnt += 1.f;
        }
    }
    #pragma unroll
    for (int off = 32; off > 0; off >>= 1) {
        sum += __shfl_down(sum, off);
        cnt += __shfl_down(cnt, off);
    }
    if ((tid & 63) == 0) { red[tid >> 6][0] = sum; red[tid >> 6][1] = cnt; }
    __syncthreads();
    if (tid == 0) {
        sum = red[0][0] + red[1][0] + red[2][0] + red[3][0];
        cnt = red[0][1] + red[1][1] + red[2][1] + red[3][1];
        bool valid = (cnt > 0.f) && !(ps == 0 && pe == 0);
        float v = valid ? (sum / fmaxf(cnt, 1.f)) : 0.f;
        out[b * P_ + p] = v + fcb[0];
    }
}

extern "C" void kernel_launch(void* const* d_in, const int* in_sizes, int n_in,
                              void* d_out, int out_size, void* d_ws, size_t ws_size,
                              hipStream_t stream) {
    const float* emb   = (const float*)d_in[0];
    const float* wih_f = (const float*)d_in[1];
    const float* whh_f = (const float*)d_in[2];
    const float* bih_f = (const float*)d_in[3];
    const float* bhh_f = (const float*)d_in[4];
    const float* wih_b = (const float*)d_in[5];
    const float* whh_b = (const float*)d_in[6];
    const float* bih_b = (const float*)d_in[7];
    const float* bhh_b = (const float*)d_in[8];
    const float* fc_w  = (const float*)d_in[9];
    const float* fc_b  = (const float*)d_in[10];
    const int* ids     = (const int*)d_in[11];
    const int* om      = (const int*)d_in[13];
    const int* pos     = (const int*)d_in[14];

    char* ws = (char*)d_ws;
    f16*   X     = (f16*)(ws + 0);            // 64*1024*128*2       = 16,777,216
    f16*   Wsw   = (f16*)(ws + 16777216);     // 16*48*128*8*2       =  1,572,864
    float* bias2 = (float*)(ws + 18350080);   // 2048*4              =      8,192
    f16*   Hx    = (f16*)(ws + 18358272);     // 256*2*128*2         =    131,072
    u32*   flags = (u32*)(ws + 18489344);     // 256*4               =      1,024
    float* Svp   = (float*)(ws + 18490368);   // 4*64*1024*4         =  1,048,576
    float* out   = (float*)d_out;             // total ws use ≈ 19.5 MB

    k_prep_w<<<2048, 384, 0, stream>>>(wih_f, whh_f, bih_f, bhh_f,
                                       wih_b, whh_b, bih_b, bhh_b, Wsw, bias2);
    k_gather<<<32768, 256, 0, stream>>>(ids, emb, X);
    k_zero<<<1, 256, 0, stream>>>(flags);
    k_lstm<<<256, 256, 0, stream>>>(Wsw, bias2, X, fc_w, Hx, flags, Svp);
    k_pool<<<2048, 256, 0, stream>>>(Svp, om, pos, fc_b, out);
}

// Round 4
// 8116.873 us; speedup vs baseline: 2.3603x; 2.1551x over previous
//
#include <hip/hip_runtime.h>

#define S_  1024
#define B_  64
#define P_  32

typedef _Float16 f16;
typedef unsigned int u32;
typedef _Float16 half2_t __attribute__((ext_vector_type(2)));
typedef _Float16 half8_t __attribute__((ext_vector_type(8)));

__device__ __forceinline__ float dot8(half8_t w, half8_t h, float acc) {
#if __has_builtin(__builtin_amdgcn_fdot2)
    acc = __builtin_amdgcn_fdot2((half2_t){w[0], w[1]}, (half2_t){h[0], h[1]}, acc, false);
    acc = __builtin_amdgcn_fdot2((half2_t){w[2], w[3]}, (half2_t){h[2], h[3]}, acc, false);
    acc = __builtin_amdgcn_fdot2((half2_t){w[4], w[5]}, (half2_t){h[4], h[5]}, acc, false);
    acc = __builtin_amdgcn_fdot2((half2_t){w[6], w[7]}, (half2_t){h[6], h[7]}, acc, false);
#else
    #pragma unroll
    for (int j = 0; j < 8; ++j) acc += (float)w[j] * (float)h[j];
#endif
    return acc;
}

__device__ __forceinline__ float fast_sig(float x)  { return 1.f / (1.f + __expf(-x)); }
__device__ __forceinline__ float fast_tanh(float x) { return 1.f - 2.f / (1.f + __expf(2.f * x)); }

// ---- prep: split weights into register-part and LDS-part, swizzled for coalescing ----
// For gate row r (within dir): g=r>>8, half=(r>>7)&1, up=r&127, rid=g*128+up (row-in-block).
// Wreg[dir][half][part 0=x,1=own-h][c 16][rid 512][8]   (64 VGPR-chunks worth per thread)
// Wlds[dir][half][c 16][rid 512][8]                      (partner-half Whh columns)
__global__ void k_prep_w(const float* __restrict__ wih_f, const float* __restrict__ whh_f,
                         const float* __restrict__ bih_f, const float* __restrict__ bhh_f,
                         const float* __restrict__ wih_b, const float* __restrict__ whh_b,
                         const float* __restrict__ bih_b, const float* __restrict__ bhh_b,
                         f16* __restrict__ Wreg, f16* __restrict__ Wlds,
                         float* __restrict__ bias2) {
    int rowg = blockIdx.x;          // 0..2047
    int dir = rowg >> 10;
    int r = rowg & 1023;
    int col = threadIdx.x;          // 0..383
    int g = r >> 8, rem = r & 255, half = rem >> 7, up = rem & 127;
    int rid = g * 128 + up;
    const float* wih = dir ? wih_b : wih_f;
    const float* whh = dir ? whh_b : whh_f;
    if (col < 128) {
        float v = wih[r * 128 + col];
        Wreg[((((size_t)(dir * 2 + half) * 2 + 0) * 16 + (col >> 3)) * 512 + rid) * 8 + (col & 7)] = (f16)v;
    } else {
        int k = col - 128;                 // 0..255 column of Whh
        float v = whh[r * 256 + k];
        int hc = k >> 7, kk = k & 127, c = kk >> 3, j = kk & 7;
        if (hc == half)
            Wreg[((((size_t)(dir * 2 + half) * 2 + 1) * 16 + c) * 512 + rid) * 8 + j] = (f16)v;
        else
            Wlds[(((size_t)(dir * 2 + half) * 16 + c) * 512 + rid) * 8 + j] = (f16)v;
    }
    if (col == 0) {
        const float* bi = dir ? bih_b : bih_f;
        const float* bh = dir ? bhh_b : bhh_f;
        bias2[rowg] = bi[r] + bh[r];
    }
}

// ---- embedding gather -> f16 X[b][t][128] ----
__global__ void k_gather(const int* __restrict__ ids, const float* __restrict__ emb,
                         f16* __restrict__ X) {
    int m = blockIdx.x * 2 + (threadIdx.x >> 7);
    int k = threadIdx.x & 127;
    int id = ids[m];
    X[(size_t)m * 128 + k] = (f16)emb[(size_t)id * 128 + k];
}

// ---- zero the sync flags (ws is poisoned 0xAA before every launch) ----
__global__ void k_zero(u32* __restrict__ flags) {
    flags[threadIdx.x] = 0u;
}

// ---- recurrence: 256 blocks = 2 dir x 2 half x 64 batch; 512 thr, 1 row/thread ----
// Weights: 32 chunks (x + own-h) in VGPRs, 16 chunks (partner-h) in LDS.
__global__ __launch_bounds__(512, 1) void k_lstm(
        const f16* __restrict__ Wreg,    // [2][2][2][16][512][8]
        const f16* __restrict__ Wlds,    // [2][2][16][512][8]
        const float* __restrict__ bias2, // [2][1024]
        const f16* __restrict__ X,       // [64][1024][128]
        const float* __restrict__ fcw,   // [512]
        f16* __restrict__ Hx,            // [256 slots][2 parity][128]
        u32* __restrict__ flags,         // [256]
        float* __restrict__ Svp) {       // [4][64][1024]
    __shared__ __align__(16) f16 sh_w[16 * 512 * 8];  // 128 KB partner-half weights
    __shared__ __align__(16) f16 sh_h[256];           // [half0 u128 | half1 u128]
    __shared__ float zbuf[4][128];

    const int blk  = blockIdx.x;
    const int dir  = blk >> 7;
    const int half = (blk >> 6) & 1;
    const int b    = blk & 63;
    const int tid  = threadIdx.x;     // == rid (row-in-block)
    const int g    = tid >> 7;        // gate 0..3 (wave-uniform: 2 waves per gate)
    const int up   = tid & 127;
    const int row  = g * 256 + half * 128 + up;   // gate row in [0,1024)

    // ---- register weights: 32 chunks of 8 f16 = 128 VGPRs ----
    const half8_t* wrg = (const half8_t*)Wreg;
    const size_t base_x = (((size_t)(dir * 2 + half) * 2 + 0) * 16) * 512 + tid;
    const size_t base_h = (((size_t)(dir * 2 + half) * 2 + 1) * 16) * 512 + tid;
    half8_t wx[16], wh[16];
    #pragma unroll
    for (int c = 0; c < 16; ++c) wx[c] = wrg[base_x + (size_t)c * 512];
    #pragma unroll
    for (int c = 0; c < 16; ++c) wh[c] = wrg[base_h + (size_t)c * 512];

    // ---- stage partner-half weights into LDS (conflict-free [chunk][row] layout) ----
    {
        const half8_t* wlg = (const half8_t*)Wlds + ((size_t)(dir * 2 + half) * 16) * 512 + tid;
        half8_t* shw = (half8_t*)sh_w;
        #pragma unroll
        for (int c = 0; c < 16; ++c) shw[c * 512 + tid] = wlg[(size_t)c * 512];
    }

    const float bias = bias2[dir * 1024 + row];

    const f16* Xb = X + (size_t)b * S_ * 128;
    const int fidx_own = (dir * 64 + b) * 2 + half;
    const int fidx_par = fidx_own ^ 1;
    f16*       hx_own = Hx + (size_t)fidx_own * 2 * 128;
    const f16* hx_par = Hx + (size_t)fidx_par * 2 * 128;

    // combine-wave state (wave 0, 2 u's per lane)
    float c0 = 0.f, c1 = 0.f, fc0 = 0.f, fc1 = 0.f;
    if (tid < 64) {
        fc0 = fcw[dir * 256 + half * 128 + 2 * tid];
        fc1 = fcw[dir * 256 + half * 128 + 2 * tid + 1];
    }

    // init LDS h = 0 (both halves)
    if (tid < 128) ((u32*)sh_h)[tid] = 0u;
    __syncthreads();

    const half8_t* shh = (const half8_t*)sh_h;    // 32 chunks of 8 f16
    const half8_t* shw = (const half8_t*)sh_w;
    const int ownc = half * 16;
    const int parc = (1 - half) * 16;

    for (int s = 0; s < S_; ++s) {
        const int t = dir ? (S_ - 1 - s) : s;
        const half8_t* xrow = (const half8_t*)&Xb[(size_t)t * 128];

        float a0 = 0.f, a1 = 0.f, a2 = 0.f, a3 = 0.f;

        // ---- phase 1: own-half h dots (LDS broadcast) + x dots (global uniform) ----
        #pragma unroll
        for (int c = 0; c < 16; c += 2) {
            a0 = dot8(wh[c],     shh[ownc + c],     a0);
            a1 = dot8(wh[c + 1], shh[ownc + c + 1], a1);
        }
        #pragma unroll
        for (int c = 0; c < 16; c += 2) {
            a2 = dot8(wx[c],     xrow[c],     a2);
            a3 = dot8(wx[c + 1], xrow[c + 1], a3);
        }

        // ---- wave 0: wait for partner h_s, stage into LDS ----
        if (s > 0 && tid < 64) {
            if (tid == 0) {
                while (__hip_atomic_load(&flags[fidx_par], __ATOMIC_ACQUIRE,
                                         __HIP_MEMORY_SCOPE_AGENT) < (u32)s)
                    __builtin_amdgcn_s_sleep(1);
            }
            if (tid < 16)
                *(half8_t*)&sh_h[(1 - half) * 128 + tid * 8] =
                    *(const half8_t*)&hx_par[(size_t)(s & 1) * 128 + tid * 8];
        }
        __syncthreads();   // B1: partner h staged

        // ---- phase 3: partner-half h dots, weights from LDS ----
        #pragma unroll
        for (int c = 0; c < 16; c += 2) {
            half8_t w0 = shw[c * 512 + tid];
            half8_t w1 = shw[(c + 1) * 512 + tid];
            a0 = dot8(w0, shh[parc + c],     a0);
            a1 = dot8(w1, shh[parc + c + 1], a1);
        }

        float z = a0 + a1 + a2 + a3 + bias;
        float act = (g == 2) ? fast_tanh(z) : fast_sig(z);
        zbuf[g][up] = act;
        __syncthreads();   // B2: all gate activations ready

        // ---- wave 0: combine (2 u's/lane), publish h, partial FC dot ----
        if (tid < 64) {
            const int u0 = 2 * tid, u1 = u0 + 1;
            float i0 = zbuf[0][u0], f0 = zbuf[1][u0], g0 = zbuf[2][u0], o0 = zbuf[3][u0];
            float i1 = zbuf[0][u1], f1 = zbuf[1][u1], g1 = zbuf[2][u1], o1 = zbuf[3][u1];
            c0 = f0 * c0 + i0 * g0;
            c1 = f1 * c1 + i1 * g1;
            float h0 = o0 * fast_tanh(c0);
            float h1 = o1 * fast_tanh(c1);
            f16 h0h = (f16)h0, h1h = (f16)h1;
            u32 packed = (u32)__builtin_bit_cast(unsigned short, h0h)
                       | ((u32)__builtin_bit_cast(unsigned short, h1h) << 16);
            ((u32*)&sh_h[half * 128])[tid] = packed;                    // own half for next step
            ((u32*)&hx_own[(size_t)((s + 1) & 1) * 128])[tid] = packed; // publish to partner
            float ps = h0 * fc0 + h1 * fc1;
            #pragma unroll
            for (int off = 32; off > 0; off >>= 1) ps += __shfl_down(ps, off);
            if (tid == 0) {
                __hip_atomic_store(&flags[fidx_own], (u32)(s + 1), __ATOMIC_RELEASE,
                                   __HIP_MEMORY_SCOPE_AGENT);
                Svp[(((size_t)half * 2 + dir) * 64 + b) * S_ + t] = ps;
            }
        }
        __syncthreads();   // B3: h_{s+1} own half staged; zbuf consumed
    }
}

// ---- span pooling + FC ----
__global__ __launch_bounds__(256) void k_pool(const float* __restrict__ Svp, // [4][64][1024]
                                              const int* __restrict__ om,    // [64][1024][2]
                                              const int* __restrict__ pos,   // [64][32][2]
                                              const float* __restrict__ fcb,
                                              float* __restrict__ out) {     // [64][32]
    __shared__ float red[4][2];
    int bp = blockIdx.x;
    int b = bp >> 5, p = bp & 31;
    int ps = pos[(b * P_ + p) * 2];
    int pe = pos[(b * P_ + p) * 2 + 1];
    int tid = threadIdx.x;
    float sum = 0.f, cnt = 0.f;
    for (int j = tid; j < S_; j += 256) {
        int os = om[((size_t)b * S_ + j) * 2];
        int oe = om[((size_t)b * S_ + j) * 2 + 1];
        if (os >= ps && oe <= pe) {
            size_t base = (size_t)b * S_ + j;
            sum += Svp[0 * 65536 + base] + Svp[1 * 65536 + base]
                 + Svp[2 * 65536 + base] + Svp[3 * 65536 + base];
            cnt += 1.f;
        }
    }
    #pragma unroll
    for (int off = 32; off > 0; off >>= 1) {
        sum += __shfl_down(sum, off);
        cnt += __shfl_down(cnt, off);
    }
    if ((tid & 63) == 0) { red[tid >> 6][0] = sum; red[tid >> 6][1] = cnt; }
    __syncthreads();
    if (tid == 0) {
        sum = red[0][0] + red[1][0] + red[2][0] + red[3][0];
        cnt = red[0][1] + red[1][1] + red[2][1] + red[3][1];
        bool valid = (cnt > 0.f) && !(ps == 0 && pe == 0);
        float v = valid ? (sum / fmaxf(cnt, 1.f)) : 0.f;
        out[b * P_ + p] = v + fcb[0];
    }
}

extern "C" void kernel_launch(void* const* d_in, const int* in_sizes, int n_in,
                              void* d_out, int out_size, void* d_ws, size_t ws_size,
                              hipStream_t stream) {
    const float* emb   = (const float*)d_in[0];
    const float* wih_f = (const float*)d_in[1];
    const float* whh_f = (const float*)d_in[2];
    const float* bih_f = (const float*)d_in[3];
    const float* bhh_f = (const float*)d_in[4];
    const float* wih_b = (const float*)d_in[5];
    const float* whh_b = (const float*)d_in[6];
    const float* bih_b = (const float*)d_in[7];
    const float* bhh_b = (const float*)d_in[8];
    const float* fc_w  = (const float*)d_in[9];
    const float* fc_b  = (const float*)d_in[10];
    const int* ids     = (const int*)d_in[11];
    const int* om      = (const int*)d_in[13];
    const int* pos     = (const int*)d_in[14];

    char* ws = (char*)d_ws;
    f16*   X     = (f16*)(ws + 0);            // 64*1024*128*2        = 16,777,216
    f16*   Wreg  = (f16*)(ws + 16777216);     // 2*2*2*16*512*8*2     =  1,048,576
    f16*   Wlds  = (f16*)(ws + 17825792);     // 2*2*16*512*8*2       =    524,288
    float* bias2 = (float*)(ws + 18350080);   // 2048*4               =      8,192
    f16*   Hx    = (f16*)(ws + 18358272);     // 256*2*128*2          =    131,072
    u32*   flags = (u32*)(ws + 18489344);     // 256*4                =      1,024
    float* Svp   = (float*)(ws + 18490368);   // 4*64*1024*4          =  1,048,576
    float* out   = (float*)d_out;             // total ws use ≈ 19.5 MB

    k_prep_w<<<2048, 384, 0, stream>>>(wih_f, whh_f, bih_f, bhh_f,
                                       wih_b, whh_b, bih_b, bhh_b, Wreg, Wlds, bias2);
    k_gather<<<32768, 256, 0, stream>>>(ids, emb, X);
    k_zero<<<1, 256, 0, stream>>>(flags);
    k_lstm<<<256, 512, 0, stream>>>(Wreg, Wlds, bias2, X, fc_w, Hx, flags, Svp);
    k_pool<<<2048, 256, 0, stream>>>(Svp, om, pos, fc_b, out);
}